// Round 11
// baseline (299.023 us; speedup 1.0000x reference)
//
#include <hip/hip_runtime.h>

typedef unsigned short u16;
typedef __attribute__((ext_vector_type(8))) short bf16x8;   // 8 bf16 in 4 VGPRs (MFMA A/B frag)
typedef __attribute__((ext_vector_type(4))) float f32x4;    // MFMA C/D frag

#define SS 2048
#define EE 1024
#define HH 16
#define DD 64

__device__ __forceinline__ float b2f(u16 u) {
  union { unsigned int i; float f; } v; v.i = ((unsigned int)u) << 16; return v.f;
}
__device__ __forceinline__ u16 f2b(float f) {
  union { float f; unsigned int i; } v; v.f = f;
  unsigned int i = v.i;
  return (u16)((i + 0x7FFFu + ((i >> 16) & 1u)) >> 16);  // RNE
}

// ---------------- fp32 -> bf16 convert (weights) ----------------
__global__ __launch_bounds__(256) void k_cvt(const float* __restrict__ src,
                                             u16* __restrict__ dst) {
  const int i = blockIdx.x * 256 + threadIdx.x;
  float4 v = ((const float4*)src)[i];
  ushort4 o;
  o.x = f2b(v.x); o.y = f2b(v.y); o.z = f2b(v.z); o.w = f2b(v.w);
  ((ushort4*)dst)[i] = o;
}

// ---------------- LayerNorm (fp32 in -> bf16 out) ----------------
__global__ __launch_bounds__(256) void k_ln(const float* __restrict__ x,
                                            const float* __restrict__ lw,
                                            const float* __restrict__ lb,
                                            u16* __restrict__ xn) {
  const int row = blockIdx.x, t = threadIdx.x;
  float4 v = ((const float4*)(x + (size_t)row * EE))[t];
  float f0 = v.x, f1 = v.y, f2 = v.z, f3 = v.w;
  float s = f0 + f1 + f2 + f3;
  float ss = f0 * f0 + f1 * f1 + f2 * f2 + f3 * f3;
  for (int o = 1; o < 64; o <<= 1) { s += __shfl_xor(s, o); ss += __shfl_xor(ss, o); }
  __shared__ float red[8];
  int w = t >> 6;
  if ((t & 63) == 0) { red[w] = s; red[4 + w] = ss; }
  __syncthreads();
  s = red[0] + red[1] + red[2] + red[3];
  ss = red[4] + red[5] + red[6] + red[7];
  float mu = s * (1.0f / 1024.0f);
  float var = ss * (1.0f / 1024.0f) - mu * mu;
  float rstd = rsqrtf(var + 1e-5f);
  float4 wv = ((const float4*)lw)[t];
  float4 bv = ((const float4*)lb)[t];
  ushort4 o;
  o.x = f2b((f0 - mu) * rstd * wv.x + bv.x);
  o.y = f2b((f1 - mu) * rstd * wv.y + bv.y);
  o.z = f2b((f2 - mu) * rstd * wv.z + bv.z);
  o.w = f2b((f3 - mu) * rstd * wv.w + bv.w);
  ((ushort4*)(xn + (size_t)row * EE))[t] = o;
}

// ---- MFMA GEMM  C[M,N] = A[M,K] * W[N,K]^T + bias; bf16 or fp32 output ----
template <typename OutT>
__device__ __forceinline__ void gemm_body(const u16* __restrict__ A,
                                          const u16* __restrict__ W,
                                          const float* __restrict__ bias,
                                          OutT* __restrict__ C,
                                          int M, int N, int K) {
  __shared__ __align__(16) u16 As[128 * 40];
  __shared__ __align__(16) u16 Ws[128 * 40];
  const int t = threadIdx.x;
  const int m0 = blockIdx.y * 128, n0 = blockIdx.x * 128;
  const int lane = t & 63, w = t >> 6, quad = lane >> 4, l15 = lane & 15;
  const int wm = (w & 1) * 64, wn = (w >> 1) * 64;
  const int srow = t >> 2, sc = t & 3;

  f32x4 zero4 = {0.f, 0.f, 0.f, 0.f};
  f32x4 acc[4][4];
  for (int mi = 0; mi < 4; mi++)
    for (int ni = 0; ni < 4; ni++) acc[mi][ni] = zero4;

  const u16* Ag = A + (size_t)(m0 + srow) * K + sc * 8;
  const u16* Wg = W + (size_t)(n0 + srow) * K + sc * 8;
  const size_t rowskip = (size_t)64 * K;

  for (int k0 = 0; k0 < K; k0 += 32) {
    bf16x8 a0 = *(const bf16x8*)(Ag + k0);
    bf16x8 a1 = *(const bf16x8*)(Ag + rowskip + k0);
    bf16x8 w0 = *(const bf16x8*)(Wg + k0);
    bf16x8 w1 = *(const bf16x8*)(Wg + rowskip + k0);
    *(bf16x8*)(As + srow * 40 + sc * 8) = a0;
    *(bf16x8*)(As + (srow + 64) * 40 + sc * 8) = a1;
    *(bf16x8*)(Ws + srow * 40 + sc * 8) = w0;
    *(bf16x8*)(Ws + (srow + 64) * 40 + sc * 8) = w1;
    __syncthreads();
    bf16x8 af[4], wf[4];
#pragma unroll
    for (int i = 0; i < 4; i++) {
      af[i] = *(const bf16x8*)(As + (wm + i * 16 + l15) * 40 + quad * 8);
      wf[i] = *(const bf16x8*)(Ws + (wn + i * 16 + l15) * 40 + quad * 8);
    }
#pragma unroll
    for (int mi = 0; mi < 4; mi++)
#pragma unroll
      for (int ni = 0; ni < 4; ni++)
        acc[mi][ni] = __builtin_amdgcn_mfma_f32_16x16x32_bf16(af[mi], wf[ni], acc[mi][ni], 0, 0, 0);
    __syncthreads();
  }
  // epilogue: D row = quad*4+reg, col = l15 (verified m89 layout; cross-checked R2==R3)
  for (int mi = 0; mi < 4; mi++)
    for (int ni = 0; ni < 4; ni++) {
      int col = n0 + wn + ni * 16 + l15;
      float bb = bias[col];
      for (int r = 0; r < 4; r++) {
        int grow = m0 + wm + mi * 16 + quad * 4 + r;
        float val = acc[mi][ni][r] + bb;
        if constexpr (sizeof(OutT) == 2) C[(size_t)grow * N + col] = f2b(val);
        else                             C[(size_t)grow * N + col] = val;
      }
    }
}

__global__ __launch_bounds__(256) void k_gemm_b(const u16* A, const u16* W,
                                                const float* bias, u16* C,
                                                int M, int N, int K) {
  gemm_body<u16>(A, W, bias, C, M, N, K);
}
__global__ __launch_bounds__(256) void k_gemm_f(const u16* A, const u16* W,
                                                const float* bias, float* C,
                                                int M, int N, int K) {
  gemm_body<float>(A, W, bias, C, M, N, K);
}

// ------ rotate (fixed angle) + per-head l2norm + qknorm scale, in place on q,k ------
__global__ __launch_bounds__(256) void k_rotnorm(u16* __restrict__ qkv,
                                                 const float* __restrict__ inv_freq,
                                                 const float* __restrict__ scale_p) {
  __shared__ float qf[1024];
  __shared__ float kf[1024];
  const int row = blockIdx.x, t = threadIdx.x;
  u16* qr = qkv + (size_t)row * 3072;
  u16* kr = qr + 1024;
  ushort4 qv = ((const ushort4*)qr)[t];
  ushort4 kv = ((const ushort4*)kr)[t];
  qf[4 * t + 0] = b2f(qv.x); qf[4 * t + 1] = b2f(qv.y);
  qf[4 * t + 2] = b2f(qv.z); qf[4 * t + 3] = b2f(qv.w);
  kf[4 * t + 0] = b2f(kv.x); kf[4 * t + 1] = b2f(kv.y);
  kf[4 * t + 2] = b2f(kv.z); kf[4 * t + 3] = b2f(kv.w);
  __syncthreads();
  const float scale = scale_p[0];
  float rq[4], rk[4];
#pragma unroll
  for (int u = 0; u < 4; u++) {
    int j = 4 * t + u;
    float th = 2048.0f * inv_freq[j];
    float cs = cosf(th), sn = sinf(th);
    float qrot = (j < 512) ? -qf[2 * j + 1] : qf[2 * (j - 512)];
    float krot = (j < 512) ? -kf[2 * j + 1] : kf[2 * (j - 512)];
    rq[u] = qf[j] * cs + qrot * sn;
    rk[u] = kf[j] * cs + krot * sn;
  }
  float ssq = rq[0] * rq[0] + rq[1] * rq[1] + rq[2] * rq[2] + rq[3] * rq[3];
  float ssk = rk[0] * rk[0] + rk[1] * rk[1] + rk[2] * rk[2] + rk[3] * rk[3];
  for (int o = 1; o < 16; o <<= 1) { ssq += __shfl_xor(ssq, o); ssk += __shfl_xor(ssk, o); }
  float qs = scale / fmaxf(sqrtf(ssq), 1e-12f);
  float ks = scale / fmaxf(sqrtf(ssk), 1e-12f);
  ushort4 qo, ko;
  qo.x = f2b(rq[0] * qs); qo.y = f2b(rq[1] * qs); qo.z = f2b(rq[2] * qs); qo.w = f2b(rq[3] * qs);
  ko.x = f2b(rk[0] * ks); ko.y = f2b(rk[1] * ks); ko.z = f2b(rk[2] * ks); ko.w = f2b(rk[3] * ks);
  ((ushort4*)qr)[t] = qo;
  ((ushort4*)kr)[t] = ko;
}

// ---------------- V transpose -> vt[(b,h), d, s] ----------------
__global__ __launch_bounds__(256) void k_vtrans(const u16* __restrict__ qkv,
                                                u16* __restrict__ vt) {
  __shared__ __align__(16) u16 tile[64 * 72];
  const int st = blockIdx.x, bh = blockIdx.y;
  const int b = bh >> 4, h = bh & 15;
  const int s0 = st * 64, t = threadIdx.x;
  const int si = t >> 2, dc = t & 3;
  const u16* src = qkv + (size_t)(b * SS + s0 + si) * 3072 + 2048 + h * DD;
  bf16x8 v0 = *(const bf16x8*)(src + dc * 8);
  bf16x8 v1 = *(const bf16x8*)(src + (dc + 4) * 8);
#pragma unroll
  for (int u = 0; u < 8; u++) tile[(dc * 8 + u) * 72 + si] = (u16)v0[u];
#pragma unroll
  for (int u = 0; u < 8; u++) tile[((dc + 4) * 8 + u) * 72 + si] = (u16)v1[u];
  __syncthreads();
#pragma unroll
  for (int it = 0; it < 2; it++) {
    int idx = t + it * 256;
    int d = idx >> 3, ch = idx & 7;
    bf16x8 o = *(const bf16x8*)(tile + d * 72 + ch * 8);
    *(bf16x8*)(vt + (size_t)(bh * DD + d) * SS + s0 + ch * 8) = o;
  }
}

// ---------------- causal flash attention (MFMA) ----------------
__global__ __launch_bounds__(256) void k_attn(const u16* __restrict__ qkv,
                                              const u16* __restrict__ vt,
                                              u16* __restrict__ out) {
  __shared__ __align__(16) u16 Kt[64 * 72];
  __shared__ __align__(16) u16 Vt[64 * 72];
  __shared__ __align__(16) u16 Pt[64 * 72];
  const int qt = blockIdx.x, bh = blockIdx.y;
  const int b = bh >> 4, h = bh & 15;
  const int q0 = qt * 64;
  const int t = threadIdx.x, w = t >> 6, lane = t & 63, quad = lane >> 4, l15 = lane & 15;
  const u16* qn = qkv;
  const u16* kn = qkv + 1024;

  bf16x8 qf[2];
  {
    const u16* qrow = qn + (size_t)(b * SS + q0 + 16 * w + l15) * 3072 + h * DD;
    qf[0] = *(const bf16x8*)(qrow + quad * 8);
    qf[1] = *(const bf16x8*)(qrow + 32 + quad * 8);
  }
  f32x4 zero4 = {0.f, 0.f, 0.f, 0.f};
  f32x4 oacc[4];
  for (int n = 0; n < 4; n++) oacc[n] = zero4;
  float m_i[4] = {-1e30f, -1e30f, -1e30f, -1e30f};
  float l_i[4] = {0.f, 0.f, 0.f, 0.f};
  const int sr = t >> 2, sc = t & 3;

  for (int kt = 0; kt <= qt; kt++) {
    const int k0 = kt * 64;
    const u16* krow = kn + (size_t)(b * SS + k0 + sr) * 3072 + h * DD;
    bf16x8 kv0 = *(const bf16x8*)(krow + sc * 8);
    bf16x8 kv1 = *(const bf16x8*)(krow + (sc + 4) * 8);
    const u16* vrow = vt + (size_t)(bh * DD + sr) * SS + k0;
    bf16x8 vv0 = *(const bf16x8*)(vrow + sc * 8);
    bf16x8 vv1 = *(const bf16x8*)(vrow + (sc + 4) * 8);
    *(bf16x8*)(Kt + sr * 72 + sc * 8) = kv0;
    *(bf16x8*)(Kt + sr * 72 + (sc + 4) * 8) = kv1;
    *(bf16x8*)(Vt + sr * 72 + sc * 8) = vv0;
    *(bf16x8*)(Vt + sr * 72 + (sc + 4) * 8) = vv1;
    __syncthreads();
    f32x4 sacc[4];
#pragma unroll
    for (int n = 0; n < 4; n++) {
      sacc[n] = zero4;
#pragma unroll
      for (int c = 0; c < 2; c++) {
        bf16x8 kfrag = *(const bf16x8*)(Kt + (n * 16 + l15) * 72 + c * 32 + quad * 8);
        sacc[n] = __builtin_amdgcn_mfma_f32_16x16x32_bf16(qf[c], kfrag, sacc[n], 0, 0, 0);
      }
    }
    if (kt == qt) {
#pragma unroll
      for (int n = 0; n < 4; n++)
#pragma unroll
        for (int r = 0; r < 4; r++)
          if (n * 16 + l15 > 16 * w + quad * 4 + r) sacc[n][r] = -1e30f;
    }
#pragma unroll
    for (int r = 0; r < 4; r++) {
      float mx = fmaxf(fmaxf(sacc[0][r], sacc[1][r]), fmaxf(sacc[2][r], sacc[3][r]));
      for (int o = 1; o < 16; o <<= 1) mx = fmaxf(mx, __shfl_xor(mx, o));
      float mn = fmaxf(m_i[r], mx);
      float al = __expf(m_i[r] - mn);
      m_i[r] = mn;
      float rs = 0.f;
#pragma unroll
      for (int n = 0; n < 4; n++) {
        float p = __expf(sacc[n][r] - mn);
        sacc[n][r] = p;
        rs += p;
      }
      for (int o = 1; o < 16; o <<= 1) rs += __shfl_xor(rs, o);
      l_i[r] = al * l_i[r] + rs;
#pragma unroll
      for (int n = 0; n < 4; n++) oacc[n][r] *= al;
    }
#pragma unroll
    for (int n = 0; n < 4; n++)
#pragma unroll
      for (int r = 0; r < 4; r++)
        Pt[(16 * w + quad * 4 + r) * 72 + n * 16 + l15] = f2b(sacc[n][r]);
    __syncthreads();
#pragma unroll
    for (int c = 0; c < 2; c++) {
      bf16x8 pf = *(const bf16x8*)(Pt + (16 * w + l15) * 72 + c * 32 + quad * 8);
#pragma unroll
      for (int n = 0; n < 4; n++) {
        bf16x8 vf = *(const bf16x8*)(Vt + (n * 16 + l15) * 72 + c * 32 + quad * 8);
        oacc[n] = __builtin_amdgcn_mfma_f32_16x16x32_bf16(pf, vf, oacc[n], 0, 0, 0);
      }
    }
    __syncthreads();
  }
  for (int n = 0; n < 4; n++)
    for (int r = 0; r < 4; r++) {
      int row = q0 + 16 * w + quad * 4 + r;
      out[(size_t)(b * SS + row) * EE + h * DD + n * 16 + l15] = f2b(oacc[n][r] / l_i[r]);
    }
}

extern "C" void kernel_launch(void* const* d_in, const int* in_sizes, int n_in,
                              void* d_out, int out_size, void* d_ws, size_t ws_size,
                              hipStream_t stream) {
  const float* x       = (const float*)d_in[0];
  const float* ln_w    = (const float*)d_in[1];
  const float* ln_b    = (const float*)d_in[2];
  const float* qkv_w   = (const float*)d_in[3];
  const float* qkv_b   = (const float*)d_in[4];
  const float* qk_s    = (const float*)d_in[5];
  const float* out_w   = (const float*)d_in[6];
  const float* out_b   = (const float*)d_in[7];
  const float* inv_frq = (const float*)d_in[8];

  // ws (33.55 MB, proven extent): xn bf16 [8.39 MB] | qkv bf16 [25.17 MB]
  u16* ws   = (u16*)d_ws;
  u16* xn   = ws;                               // 4096*1024 (LN out, later attn out)
  u16* qkv  = ws + (size_t)4096 * 1024;         // 4096*3072 (q,k normalized in place)
  // d_out is fp32 [16.78 MB]; stage bf16 scratch inside it while it's dead:
  u16* wq_b = (u16*)d_out;                      // [0, 6.29 MB): bf16 qkv_w
  u16* vt   = (u16*)d_out + (size_t)4194304;    // [8.39, 16.78 MB): bf16 V^T
  u16* wo_b = qkv;                              // bf16 out_w (qkv dead after attention)

  k_cvt<<<3072, 256, 0, stream>>>(qkv_w, wq_b);
  k_ln<<<4096, 256, 0, stream>>>(x, ln_w, ln_b, xn);
  k_gemm_b<<<dim3(24, 32), 256, 0, stream>>>(xn, wq_b, qkv_b, qkv, 4096, 3072, 1024);
  k_rotnorm<<<4096, 256, 0, stream>>>(qkv, inv_frq, qk_s);
  k_vtrans<<<dim3(32, 32), 256, 0, stream>>>(qkv, vt);
  k_attn<<<dim3(32, 32), 256, 0, stream>>>(qkv, vt, xn);
  k_cvt<<<1024, 256, 0, stream>>>(out_w, wo_b);
  k_gemm_f<<<dim3(8, 32), 256, 0, stream>>>(xn, wo_b, out_b, (float*)d_out, 4096, 1024, 1024);
}